// Round 12
// baseline (513.540 us; speedup 1.0000x reference)
//
#include <hip/hip_runtime.h>
#include <hip/hip_bf16.h>

typedef __attribute__((ext_vector_type(8))) short short8;
typedef __attribute__((ext_vector_type(4))) short short4v;
typedef __attribute__((ext_vector_type(4))) float f32x4;

#define NR 8192
#define LOG2E 1.4426950408889634f

__device__ __forceinline__ short f2bf(float f) {
  return __builtin_bit_cast(short, __float2bfloat16(f));
}

// ---------------------------------------------------------------------------
// K1: HT2 = (x @ W)^T in bf16, tiled layout HT2[j>>5][f][j&31]. Epilogue
// also emits sv (log2-scaled row score) and the PRE-EXPONENTIATED column
// factors etv=2^t, etv2=2^(0.2t) so k_flash needs no transcendentals.
// ---------------------------------------------------------------------------
__global__ __launch_bounds__(256) void k_gemm_h(const float* __restrict__ x,
                                                const float* __restrict__ W,
                                                const float* __restrict__ a,
                                                short* __restrict__ HT2,
                                                float* __restrict__ sv,
                                                float* __restrict__ etv,
                                                float* __restrict__ etv2) {
  __shared__ short WT[128][136];  // pad 8 shorts -> 2-way alias (free, m136)
  const int tid = threadIdx.x;
  const int w = tid >> 6;
  const int L = tid & 63;
  const int lm = L & 15;
  const int q = L >> 4;
  const int i0 = blockIdx.x * 64;

  f32x4 acc[8];
#pragma unroll
  for (int nn = 0; nn < 8; ++nn) acc[nn] = (f32x4){0.f, 0.f, 0.f, 0.f};

  for (int kc = 0; kc < 256; kc += 128) {
    if (kc) __syncthreads();
#pragma unroll
    for (int p = 0; p < 16; ++p) {
      int idx = p * 256 + tid;  // 0..4095
      int k = idx >> 5;         // 0..127
      int f4 = (idx & 31) * 4;
      float4 v = *(const float4*)&W[(kc + k) * 128 + f4];
      WT[f4 + 0][k] = f2bf(v.x);
      WT[f4 + 1][k] = f2bf(v.y);
      WT[f4 + 2][k] = f2bf(v.z);
      WT[f4 + 3][k] = f2bf(v.w);
    }
    __syncthreads();
#pragma unroll
    for (int ks = 0; ks < 4; ++ks) {
      int row = i0 + 16 * w + lm;
      const float* xp = &x[(size_t)row * 256 + kc + ks * 32 + q * 8];
      float4 xa = *(const float4*)xp;
      float4 xb = *(const float4*)(xp + 4);
      short8 af;
      af[0] = f2bf(xa.x); af[1] = f2bf(xa.y); af[2] = f2bf(xa.z); af[3] = f2bf(xa.w);
      af[4] = f2bf(xb.x); af[5] = f2bf(xb.y); af[6] = f2bf(xb.z); af[7] = f2bf(xb.w);
#pragma unroll
      for (int nn = 0; nn < 8; ++nn) {
        short8 bf = *(const short8*)&WT[nn * 16 + lm][ks * 32 + q * 8];
        acc[nn] = __builtin_amdgcn_mfma_f32_16x16x32_bf16(af, bf, acc[nn], 0, 0, 0);
      }
    }
  }

  const int ib = i0 + 16 * w + 4 * q;  // this thread's 4 output j-rows
  const int tbase = (ib >> 5) * 4096 + (ib & 31);
  float a1v[8], a2v[8];
#pragma unroll
  for (int nn = 0; nn < 8; ++nn) {
    a1v[nn] = a[nn * 16 + lm];
    a2v[nn] = a[128 + nn * 16 + lm];
  }
  float sr[4] = {0.f, 0.f, 0.f, 0.f};
  float tr[4] = {0.f, 0.f, 0.f, 0.f};
#pragma unroll
  for (int nn = 0; nn < 8; ++nn) {
    int f = nn * 16 + lm;
    short4v o;
    o[0] = f2bf(acc[nn][0]);
    o[1] = f2bf(acc[nn][1]);
    o[2] = f2bf(acc[nn][2]);
    o[3] = f2bf(acc[nn][3]);
    *(short4v*)&HT2[tbase + f * 32] = o;
#pragma unroll
    for (int r = 0; r < 4; ++r) {
      sr[r] += acc[nn][r] * a1v[nn];
      tr[r] += acc[nn][r] * a2v[nn];
    }
  }
#pragma unroll
  for (int d = 1; d < 16; d <<= 1) {
#pragma unroll
    for (int r = 0; r < 4; ++r) {
      sr[r] += __shfl_xor(sr[r], d);
      tr[r] += __shfl_xor(tr[r], d);
    }
  }
  if (lm == 0) {
#pragma unroll
    for (int r = 0; r < 4; ++r) {
      sv[ib + r] = sr[r] * LOG2E;
      float tl = tr[r] * LOG2E;
      etv[ib + r] = __builtin_amdgcn_exp2f(tl);
      etv2[ib + r] = __builtin_amdgcn_exp2f(0.2f * tl);
    }
  }
}

// ---------------------------------------------------------------------------
// K3: flash-GAT, latency-attack round. S=16 j-splits -> 4096 one-wave blocks
// (16-tile chain, half of R11); __launch_bounds__(64,3) + 8 KB LDS -> 12
// waves/CU (1.5x R11's 8). Zero barriers. p-build is transcendental-free:
// p_pos = Es*Et, p = adj ? (p_pos>1 ? p_pos : Es2*Et2) : 0   (sign(s+t) via
// 2^(s+t)>1). adj staged one tile ahead (HBM stream); HT2/etv compiler-
// scheduled (L2-resident).
// ---------------------------------------------------------------------------
__global__ __launch_bounds__(64, 3) void k_flash(const int* __restrict__ adj,
                                                 const short* __restrict__ HT2,
                                                 const float* __restrict__ sv,
                                                 const float* __restrict__ etv,
                                                 const float* __restrict__ etv2,
                                                 float* __restrict__ part,
                                                 float* __restrict__ lpart) {
  __shared__ float eps[16 * 128];  // 8 KB, wave-private (1 wave/block)
  const int L = threadIdx.x;
  const int lm = L & 15;
  const int q = L >> 4;
  const int sp = blockIdx.x & 15;  // j-split
  const int it = blockIdx.x >> 4;  // i-tile (256 x 32 rows)
  const int i0 = it * 32;

  const int row0 = i0 + lm;
  const int row1 = row0 + 16;
  const float Es0 = __builtin_amdgcn_exp2f(sv[row0]);
  const float Es0b = __builtin_amdgcn_exp2f(0.2f * sv[row0]);
  const float Es1 = __builtin_amdgcn_exp2f(sv[row1]);
  const float Es1b = __builtin_amdgcn_exp2f(0.2f * sv[row1]);
  const size_t ar0 = (size_t)row0 * NR;
  const size_t ar1 = (size_t)row1 * NR;

  f32x4 acc[2][8];
#pragma unroll
  for (int mm = 0; mm < 2; ++mm)
#pragma unroll
    for (int nn = 0; nn < 8; ++nn) acc[mm][nn] = (f32x4){0.f, 0.f, 0.f, 0.f};
  float l0 = 0.f, l1 = 0.f;

  const int tile0 = sp * 16;  // 16 tiles per split
  // prologue: stage tile0's adj (the HBM-latency stream)
  int jb = tile0 * 32 + q * 8;
  int4 sa00 = *(const int4*)&adj[ar0 + jb];
  int4 sa01 = *(const int4*)&adj[ar0 + jb + 4];
  int4 sa10 = *(const int4*)&adj[ar1 + jb];
  int4 sa11 = *(const int4*)&adj[ar1 + jb + 4];

#pragma unroll 4
  for (int t = 0; t < 16; ++t) {
    int4 a00 = sa00, a01 = sa01, a10 = sa10, a11 = sa11;
    if (t + 1 < 16) {  // stage next tile's adj now (in flight over compute)
      int jn = (tile0 + t + 1) * 32 + q * 8;
      sa00 = *(const int4*)&adj[ar0 + jn];
      sa01 = *(const int4*)&adj[ar0 + jn + 4];
      sa10 = *(const int4*)&adj[ar1 + jn];
      sa11 = *(const int4*)&adj[ar1 + jn + 4];
    }
    const int tile = tile0 + t;
    const int jc = tile * 32 + q * 8;
    float4 et0 = *(const float4*)&etv[jc];
    float4 et1 = *(const float4*)&etv[jc + 4];
    float4 eu0 = *(const float4*)&etv2[jc];
    float4 eu1 = *(const float4*)&etv2[jc + 4];
    const short* tp = &HT2[tile * 4096 + (lm * 32 + q * 8)];
    short8 bf[8];
#pragma unroll
    for (int nn = 0; nn < 8; ++nn) bf[nn] = *(const short8*)&tp[nn * 512];

    int av0[8] = {a00.x, a00.y, a00.z, a00.w, a01.x, a01.y, a01.z, a01.w};
    int av1[8] = {a10.x, a10.y, a10.z, a10.w, a11.x, a11.y, a11.z, a11.w};
    float etl[8] = {et0.x, et0.y, et0.z, et0.w, et1.x, et1.y, et1.z, et1.w};
    float eul[8] = {eu0.x, eu0.y, eu0.z, eu0.w, eu1.x, eu1.y, eu1.z, eu1.w};
    short8 p0, p1;
#pragma unroll
    for (int e = 0; e < 8; ++e) {
      float pe0 = Es0 * etl[e];
      float pn0 = Es0b * eul[e];
      float pp0 = (av0[e] > 0) ? ((pe0 > 1.f) ? pe0 : pn0) : 0.f;
      l0 += pp0;
      p0[e] = f2bf(pp0);
      float pe1 = Es1 * etl[e];
      float pn1 = Es1b * eul[e];
      float pp1 = (av1[e] > 0) ? ((pe1 > 1.f) ? pe1 : pn1) : 0.f;
      l1 += pp1;
      p1[e] = f2bf(pp1);
    }
#pragma unroll
    for (int nn = 0; nn < 8; ++nn) {
      acc[0][nn] = __builtin_amdgcn_mfma_f32_16x16x32_bf16(p0, bf[nn], acc[0][nn], 0, 0, 0);
      acc[1][nn] = __builtin_amdgcn_mfma_f32_16x16x32_bf16(p1, bf[nn], acc[1][nn], 0, 0, 0);
    }
  }

  // epilogue: wave-private LDS transpose in 2 chunks of 16 rows (8 KB).
  // Single wave -> lgkmcnt ordering, no barrier.
#pragma unroll
  for (int mm = 0; mm < 2; ++mm) {
#pragma unroll
    for (int nn = 0; nn < 8; ++nn)
#pragma unroll
      for (int r = 0; r < 4; ++r)
        eps[(4 * q + r) * 128 + nn * 16 + lm] = acc[mm][nn][r];
    float* pbase = part + ((size_t)sp * NR + i0 + 16 * mm) * 128;
#pragma unroll
    for (int c = 0; c < 8; ++c) {
      int idx = (c * 64 + L) * 4;
      *(float4*)&pbase[idx] = *(const float4*)&eps[idx];
    }
  }

  // denominator: reduce the 4 q-replicas of each row
  l0 += __shfl_xor(l0, 16);
  l0 += __shfl_xor(l0, 32);
  l1 += __shfl_xor(l1, 16);
  l1 += __shfl_xor(l1, 32);
  if (q == 0) {
    lpart[sp * NR + row0] = l0;
    lpart[sp * NR + row1] = l1;
  }
}

// ---------------------------------------------------------------------------
// K4: out[i][f] = sum_sp part / sum_sp lpart   (float4 vectorized)
// ---------------------------------------------------------------------------
__global__ __launch_bounds__(256) void k_reduce(const float* __restrict__ part,
                                                const float* __restrict__ lpart,
                                                float* __restrict__ out, int S) {
  int idx4 = blockIdx.x * 256 + threadIdx.x;
  int idx = idx4 * 4;  // i*128+f
  int i = idx >> 7;
  float4 sum = {0.f, 0.f, 0.f, 0.f};
  for (int sp = 0; sp < S; ++sp) {
    float4 v = *(const float4*)&part[(size_t)sp * (NR * 128) + idx];
    sum.x += v.x; sum.y += v.y; sum.z += v.z; sum.w += v.w;
  }
  float l = 0.f;
  for (int sp = 0; sp < S; ++sp) l += lpart[sp * NR + i];
  float inv = (l > 0.f) ? 1.f / l : 0.f;
  float4 o = {sum.x * inv, sum.y * inv, sum.z * inv, sum.w * inv};
  *(float4*)&out[idx] = o;
}

extern "C" void kernel_launch(void* const* d_in, const int* in_sizes, int n_in,
                              void* d_out, int out_size, void* d_ws, size_t ws_size,
                              hipStream_t stream) {
  const float* x = (const float*)d_in[0];    // 8192 x 256 fp32
  const int* adj = (const int*)d_in[1];      // 8192 x 8192 int32
  const float* W = (const float*)d_in[2];    // 256 x 128 fp32
  const float* a = (const float*)d_in[3];    // 256 x 1 fp32
  float* out = (float*)d_out;                // 8192 x 128 fp32

  char* ws = (char*)d_ws;
  short* HT2 = (short*)(ws + 0);          // 2 MB  bf16 h tiled [256][128][32]
  float* sv = (float*)(ws + 2097152);     // 32 KB
  float* etv = (float*)(ws + 2129920);    // 32 KB  2^t
  float* etv2 = (float*)(ws + 2162688);   // 32 KB  2^(0.2t)
  float* lpart = (float*)(ws + 2195456);  // 16*32 KB = 512 KB
  float* part = (float*)(ws + 2719744);   // 16 * 4 MB = 64 MB

  const int S = 16;  // j-splits: 256 i-tiles x 16 = 4096 one-wave blocks

  hipLaunchKernelGGL(k_gemm_h, dim3(128), dim3(256), 0, stream, x, W, a, HT2, sv,
                     etv, etv2);
  hipLaunchKernelGGL(k_flash, dim3(256 * S), dim3(64), 0, stream, adj, HT2, sv,
                     etv, etv2, part, lpart);
  hipLaunchKernelGGL(k_reduce, dim3((NR * 128) / 1024), dim3(256), 0, stream, part,
                     lpart, out, S);
}

// Round 13
// 423.594 us; speedup vs baseline: 1.2123x; 1.2123x over previous
//
#include <hip/hip_runtime.h>
#include <hip/hip_bf16.h>

typedef __attribute__((ext_vector_type(8))) short short8;
typedef __attribute__((ext_vector_type(4))) short short4v;
typedef __attribute__((ext_vector_type(4))) float f32x4;

#define NR 8192
#define LOG2E 1.4426950408889634f

__device__ __forceinline__ short f2bf(float f) {
  return __builtin_bit_cast(short, __float2bfloat16(f));
}

// ---------------------------------------------------------------------------
// K1: HT2 = (x @ W)^T in bf16, tiled layout HT2[j>>5][f][j&31] (tile =
// 128x32 bf16 = 8 KB). Fused s,t epilogue (log2e folded). ~10 us.
// ---------------------------------------------------------------------------
__global__ __launch_bounds__(256) void k_gemm_h(const float* __restrict__ x,
                                                const float* __restrict__ W,
                                                const float* __restrict__ a,
                                                short* __restrict__ HT2,
                                                float* __restrict__ sv,
                                                float* __restrict__ tv) {
  __shared__ short WT[128][136];  // pad 8 shorts -> 2-way alias (free, m136)
  const int tid = threadIdx.x;
  const int w = tid >> 6;
  const int L = tid & 63;
  const int lm = L & 15;
  const int q = L >> 4;
  const int i0 = blockIdx.x * 64;

  f32x4 acc[8];
#pragma unroll
  for (int nn = 0; nn < 8; ++nn) acc[nn] = (f32x4){0.f, 0.f, 0.f, 0.f};

  for (int kc = 0; kc < 256; kc += 128) {
    if (kc) __syncthreads();
#pragma unroll
    for (int p = 0; p < 16; ++p) {
      int idx = p * 256 + tid;  // 0..4095
      int k = idx >> 5;         // 0..127
      int f4 = (idx & 31) * 4;
      float4 v = *(const float4*)&W[(kc + k) * 128 + f4];
      WT[f4 + 0][k] = f2bf(v.x);
      WT[f4 + 1][k] = f2bf(v.y);
      WT[f4 + 2][k] = f2bf(v.z);
      WT[f4 + 3][k] = f2bf(v.w);
    }
    __syncthreads();
#pragma unroll
    for (int ks = 0; ks < 4; ++ks) {
      int row = i0 + 16 * w + lm;
      const float* xp = &x[(size_t)row * 256 + kc + ks * 32 + q * 8];
      float4 xa = *(const float4*)xp;
      float4 xb = *(const float4*)(xp + 4);
      short8 af;
      af[0] = f2bf(xa.x); af[1] = f2bf(xa.y); af[2] = f2bf(xa.z); af[3] = f2bf(xa.w);
      af[4] = f2bf(xb.x); af[5] = f2bf(xb.y); af[6] = f2bf(xb.z); af[7] = f2bf(xb.w);
#pragma unroll
      for (int nn = 0; nn < 8; ++nn) {
        short8 bf = *(const short8*)&WT[nn * 16 + lm][ks * 32 + q * 8];
        acc[nn] = __builtin_amdgcn_mfma_f32_16x16x32_bf16(af, bf, acc[nn], 0, 0, 0);
      }
    }
  }

  const int ib = i0 + 16 * w + 4 * q;  // this thread's 4 output j-rows
  const int tbase = (ib >> 5) * 4096 + (ib & 31);
  float a1v[8], a2v[8];
#pragma unroll
  for (int nn = 0; nn < 8; ++nn) {
    a1v[nn] = a[nn * 16 + lm];
    a2v[nn] = a[128 + nn * 16 + lm];
  }
  float sr[4] = {0.f, 0.f, 0.f, 0.f};
  float tr[4] = {0.f, 0.f, 0.f, 0.f};
#pragma unroll
  for (int nn = 0; nn < 8; ++nn) {
    int f = nn * 16 + lm;
    short4v o;
    o[0] = f2bf(acc[nn][0]);
    o[1] = f2bf(acc[nn][1]);
    o[2] = f2bf(acc[nn][2]);
    o[3] = f2bf(acc[nn][3]);
    *(short4v*)&HT2[tbase + f * 32] = o;
#pragma unroll
    for (int r = 0; r < 4; ++r) {
      sr[r] += acc[nn][r] * a1v[nn];
      tr[r] += acc[nn][r] * a2v[nn];
    }
  }
#pragma unroll
  for (int d = 1; d < 16; d <<= 1) {
#pragma unroll
    for (int r = 0; r < 4; ++r) {
      sr[r] += __shfl_xor(sr[r], d);
      tr[r] += __shfl_xor(tr[r], d);
    }
  }
  if (lm == 0) {
#pragma unroll
    for (int r = 0; r < 4; ++r) {
      sv[ib + r] = sr[r] * LOG2E;
      tv[ib + r] = tr[r] * LOG2E;
    }
  }
}

// ---------------------------------------------------------------------------
// K3: flash-GAT, LDS-RESIDENT HT slice. Block = 256 thr (4 waves x 32 rows),
// grid = 64 i-tiles x 16 sp. The block's 16-tile HT2 slice (128 KB) is
// staged into 64 KB LDS in TWO phases of 8 tiles; inner loop reads B-frags
// via ds_read_b128 from an XOR-swizzled layout (2-way banks = free, m136).
// Global traffic inside the loop: ONLY the adj stream (prefetched 1 tile
// ahead; 8 waves/CU x 4 KB in flight >> latency-BW product) + 32 KB-hot tv.
// This removes the ~1000 cyc/tile serialized L2/HBM waits measured in R12
// (213 us, all pipes <25%). 4 barriers/block total. LDS 64 KB -> 2 resident
// blocks/CU = 8 waves/CU.
// ---------------------------------------------------------------------------
__global__ __launch_bounds__(256, 2) void k_flash(const int* __restrict__ adj,
                                                  const short* __restrict__ HT2,
                                                  const float* __restrict__ sv,
                                                  const float* __restrict__ tv,
                                                  float* __restrict__ part,
                                                  float* __restrict__ lpart) {
  __shared__ short lds_s[32768];  // 64 KB exactly: 8 tiles x 8 KB, swizzled
  unsigned* ldsw = (unsigned*)lds_s;
  const int tid = threadIdx.x;
  const int w = tid >> 6;
  const int L = tid & 63;
  const int lm = L & 15;
  const int q = L >> 4;
  const int sp = blockIdx.x & 15;  // j-split
  const int it = blockIdx.x >> 4;  // i-tile (64 x 128 rows)
  const int i0 = it * 128;

  const int row0 = i0 + 32 * w + lm;
  const int row1 = row0 + 16;
  const float s0 = sv[row0];
  const float s1 = sv[row1];
  const size_t ar0 = (size_t)row0 * NR;
  const size_t ar1 = (size_t)row1 * NR;

  f32x4 acc[2][8];
#pragma unroll
  for (int mm = 0; mm < 2; ++mm)
#pragma unroll
    for (int nn = 0; nn < 8; ++nn) acc[mm][nn] = (f32x4){0.f, 0.f, 0.f, 0.f};
  float l0 = 0.f, l1 = 0.f;

  const int tile0 = sp * 16;  // 16 tiles per split
  // prologue: stage tile0's adj (the only HBM stream in the loop)
  int jb = tile0 * 32 + q * 8;
  int4 sa00 = *(const int4*)&adj[ar0 + jb];
  int4 sa01 = *(const int4*)&adj[ar0 + jb + 4];
  int4 sa10 = *(const int4*)&adj[ar1 + jb];
  int4 sa11 = *(const int4*)&adj[ar1 + jb + 4];

  for (int t = 0; t < 16; ++t) {
    if ((t & 7) == 0) {  // stage phase t>>3: 8 tiles -> 64 KB LDS (swizzled)
      __syncthreads();   // prior phase's readers done
      const int pbase_t = tile0 + t;  // first tile of phase
#pragma unroll
      for (int z = 0; z < 16; ++z) {
        int id = z * 256 + tid;  // 0..4095 uint4s (16B each)
        int tt = id >> 9;        // tile in phase (512 uint4/tile)
        int k = id & 511;
        int f = k >> 2, c = k & 3;
        uint4 v = *(const uint4*)&HT2[(size_t)(pbase_t + tt) * 4096 + k * 8];
        int cs = c ^ ((f >> 1) & 3);  // XOR swizzle -> 2-way banks on read
        *(uint4*)&ldsw[tt * 2048 + f * 16 + cs * 4] = v;
      }
      __syncthreads();
    }
    // consume staged adj; prefetch next tile's adj
    int4 a00 = sa00, a01 = sa01, a10 = sa10, a11 = sa11;
    if (t + 1 < 16) {
      int jn = (tile0 + t + 1) * 32 + q * 8;
      sa00 = *(const int4*)&adj[ar0 + jn];
      sa01 = *(const int4*)&adj[ar0 + jn + 4];
      sa10 = *(const int4*)&adj[ar1 + jn];
      sa11 = *(const int4*)&adj[ar1 + jn + 4];
    }
    const int jc = (tile0 + t) * 32 + q * 8;
    float4 tv0 = *(const float4*)&tv[jc];
    float4 tv1 = *(const float4*)&tv[jc + 4];
    const int tt = t & 7;
    short8 bf[8];
#pragma unroll
    for (int nn = 0; nn < 8; ++nn) {
      int f = nn * 16 + lm;
      bf[nn] = *(const short8*)&ldsw[tt * 2048 + f * 16 + ((q ^ ((f >> 1) & 3)) * 4)];
    }

    int av0[8] = {a00.x, a00.y, a00.z, a00.w, a01.x, a01.y, a01.z, a01.w};
    int av1[8] = {a10.x, a10.y, a10.z, a10.w, a11.x, a11.y, a11.z, a11.w};
    float tvl[8] = {tv0.x, tv0.y, tv0.z, tv0.w, tv1.x, tv1.y, tv1.z, tv1.w};
    short8 p0, p1;
#pragma unroll
    for (int e = 0; e < 8; ++e) {
      // logits pre-scaled by log2e; lrelu(v) = max(v, 0.2v)
      float v0 = s0 + tvl[e];
      float e0 = fmaxf(v0, 0.2f * v0);
      float pp0 = (av0[e] > 0) ? __builtin_amdgcn_exp2f(e0) : 0.f;
      l0 += pp0;
      p0[e] = f2bf(pp0);
      float v1 = s1 + tvl[e];
      float e1 = fmaxf(v1, 0.2f * v1);
      float pp1 = (av1[e] > 0) ? __builtin_amdgcn_exp2f(e1) : 0.f;
      l1 += pp1;
      p1[e] = f2bf(pp1);
    }
#pragma unroll
    for (int nn = 0; nn < 8; ++nn) {
      acc[0][nn] = __builtin_amdgcn_mfma_f32_16x16x32_bf16(p0, bf[nn], acc[0][nn], 0, 0, 0);
      acc[1][nn] = __builtin_amdgcn_mfma_f32_16x16x32_bf16(p1, bf[nn], acc[1][nn], 0, 0, 0);
    }
  }
  __syncthreads();  // slice LDS free -> reuse for epilogue

  // epilogue: wave-private LDS transpose (8 KB region/wave), contiguous
  // float4 stores; mm chunks sequential in the same region (lgkmcnt orders).
  float* my = (float*)lds_s + w * 2048;
#pragma unroll
  for (int mm = 0; mm < 2; ++mm) {
#pragma unroll
    for (int nn = 0; nn < 8; ++nn)
#pragma unroll
      for (int r = 0; r < 4; ++r)
        my[(4 * q + r) * 128 + nn * 16 + lm] = acc[mm][nn][r];
    float* pbase = part + ((size_t)sp * NR + i0 + 32 * w + 16 * mm) * 128;
#pragma unroll
    for (int c = 0; c < 8; ++c) {
      int idx = (c * 64 + L) * 4;
      *(float4*)&pbase[idx] = *(const float4*)&my[idx];
    }
  }

  // denominator: reduce the 4 q-replicas of each row
  l0 += __shfl_xor(l0, 16);
  l0 += __shfl_xor(l0, 32);
  l1 += __shfl_xor(l1, 16);
  l1 += __shfl_xor(l1, 32);
  if (q == 0) {
    lpart[sp * NR + row0] = l0;
    lpart[sp * NR + row1] = l1;
  }
}

// ---------------------------------------------------------------------------
// K4: out[i][f] = sum_sp part / sum_sp lpart   (float4 vectorized)
// ---------------------------------------------------------------------------
__global__ __launch_bounds__(256) void k_reduce(const float* __restrict__ part,
                                                const float* __restrict__ lpart,
                                                float* __restrict__ out, int S) {
  int idx4 = blockIdx.x * 256 + threadIdx.x;
  int idx = idx4 * 4;  // i*128+f
  int i = idx >> 7;
  float4 sum = {0.f, 0.f, 0.f, 0.f};
  for (int sp = 0; sp < S; ++sp) {
    float4 v = *(const float4*)&part[(size_t)sp * (NR * 128) + idx];
    sum.x += v.x; sum.y += v.y; sum.z += v.z; sum.w += v.w;
  }
  float l = 0.f;
  for (int sp = 0; sp < S; ++sp) l += lpart[sp * NR + i];
  float inv = (l > 0.f) ? 1.f / l : 0.f;
  float4 o = {sum.x * inv, sum.y * inv, sum.z * inv, sum.w * inv};
  *(float4*)&out[idx] = o;
}

extern "C" void kernel_launch(void* const* d_in, const int* in_sizes, int n_in,
                              void* d_out, int out_size, void* d_ws, size_t ws_size,
                              hipStream_t stream) {
  const float* x = (const float*)d_in[0];    // 8192 x 256 fp32
  const int* adj = (const int*)d_in[1];      // 8192 x 8192 int32
  const float* W = (const float*)d_in[2];    // 256 x 128 fp32
  const float* a = (const float*)d_in[3];    // 256 x 1 fp32
  float* out = (float*)d_out;                // 8192 x 128 fp32

  char* ws = (char*)d_ws;
  short* HT2 = (short*)(ws + 0);          // 2 MB  bf16 h tiled [256][128][32]
  float* sv = (float*)(ws + 2097152);     // 32 KB
  float* tv = (float*)(ws + 2129920);     // 32 KB
  float* lpart = (float*)(ws + 2162688);  // 16*32 KB = 512 KB
  float* part = (float*)(ws + 2719744);   // 16 * 4 MB = 64 MB

  const int S = 16;  // j-splits: 64 i-tiles x 16 = 1024 blocks of 4 waves

  hipLaunchKernelGGL(k_gemm_h, dim3(128), dim3(256), 0, stream, x, W, a, HT2, sv, tv);
  hipLaunchKernelGGL(k_flash, dim3(64 * S), dim3(256), 0, stream, adj, HT2, sv, tv,
                     part, lpart);
  hipLaunchKernelGGL(k_reduce, dim3((NR * 128) / 1024), dim3(256), 0, stream, part,
                     lpart, out, S);
}

// Round 14
// 415.846 us; speedup vs baseline: 1.2349x; 1.0186x over previous
//
#include <hip/hip_runtime.h>
#include <hip/hip_bf16.h>

typedef __attribute__((ext_vector_type(8))) short short8;
typedef __attribute__((ext_vector_type(4))) short short4v;
typedef __attribute__((ext_vector_type(4))) float f32x4;

#define NR 8192
#define LOG2E 1.4426950408889634f

__device__ __forceinline__ short f2bf(float f) {
  return __builtin_bit_cast(short, __float2bfloat16(f));
}

// ---------------------------------------------------------------------------
// K1: HT2 = (x @ W)^T in bf16, tiled layout HT2[j>>5][f][j&31] (tile =
// 128x32 bf16 = 8 KB). Fused s,t epilogue (log2e folded). ~10 us.
// ---------------------------------------------------------------------------
__global__ __launch_bounds__(256) void k_gemm_h(const float* __restrict__ x,
                                                const float* __restrict__ W,
                                                const float* __restrict__ a,
                                                short* __restrict__ HT2,
                                                float* __restrict__ sv,
                                                float* __restrict__ tv) {
  __shared__ short WT[128][136];  // pad 8 shorts -> 2-way alias (free, m136)
  const int tid = threadIdx.x;
  const int w = tid >> 6;
  const int L = tid & 63;
  const int lm = L & 15;
  const int q = L >> 4;
  const int i0 = blockIdx.x * 64;

  f32x4 acc[8];
#pragma unroll
  for (int nn = 0; nn < 8; ++nn) acc[nn] = (f32x4){0.f, 0.f, 0.f, 0.f};

  for (int kc = 0; kc < 256; kc += 128) {
    if (kc) __syncthreads();
#pragma unroll
    for (int p = 0; p < 16; ++p) {
      int idx = p * 256 + tid;  // 0..4095
      int k = idx >> 5;         // 0..127
      int f4 = (idx & 31) * 4;
      float4 v = *(const float4*)&W[(kc + k) * 128 + f4];
      WT[f4 + 0][k] = f2bf(v.x);
      WT[f4 + 1][k] = f2bf(v.y);
      WT[f4 + 2][k] = f2bf(v.z);
      WT[f4 + 3][k] = f2bf(v.w);
    }
    __syncthreads();
#pragma unroll
    for (int ks = 0; ks < 4; ++ks) {
      int row = i0 + 16 * w + lm;
      const float* xp = &x[(size_t)row * 256 + kc + ks * 32 + q * 8];
      float4 xa = *(const float4*)xp;
      float4 xb = *(const float4*)(xp + 4);
      short8 af;
      af[0] = f2bf(xa.x); af[1] = f2bf(xa.y); af[2] = f2bf(xa.z); af[3] = f2bf(xa.w);
      af[4] = f2bf(xb.x); af[5] = f2bf(xb.y); af[6] = f2bf(xb.z); af[7] = f2bf(xb.w);
#pragma unroll
      for (int nn = 0; nn < 8; ++nn) {
        short8 bf = *(const short8*)&WT[nn * 16 + lm][ks * 32 + q * 8];
        acc[nn] = __builtin_amdgcn_mfma_f32_16x16x32_bf16(af, bf, acc[nn], 0, 0, 0);
      }
    }
  }

  const int ib = i0 + 16 * w + 4 * q;  // this thread's 4 output j-rows
  const int tbase = (ib >> 5) * 4096 + (ib & 31);
  float a1v[8], a2v[8];
#pragma unroll
  for (int nn = 0; nn < 8; ++nn) {
    a1v[nn] = a[nn * 16 + lm];
    a2v[nn] = a[128 + nn * 16 + lm];
  }
  float sr[4] = {0.f, 0.f, 0.f, 0.f};
  float tr[4] = {0.f, 0.f, 0.f, 0.f};
#pragma unroll
  for (int nn = 0; nn < 8; ++nn) {
    int f = nn * 16 + lm;
    short4v o;
    o[0] = f2bf(acc[nn][0]);
    o[1] = f2bf(acc[nn][1]);
    o[2] = f2bf(acc[nn][2]);
    o[3] = f2bf(acc[nn][3]);
    *(short4v*)&HT2[tbase + f * 32] = o;
#pragma unroll
    for (int r = 0; r < 4; ++r) {
      sr[r] += acc[nn][r] * a1v[nn];
      tr[r] += acc[nn][r] * a2v[nn];
    }
  }
#pragma unroll
  for (int d = 1; d < 16; d <<= 1) {
#pragma unroll
    for (int r = 0; r < 4; ++r) {
      sr[r] += __shfl_xor(sr[r], d);
      tr[r] += __shfl_xor(tr[r], d);
    }
  }
  if (lm == 0) {
#pragma unroll
    for (int r = 0; r < 4; ++r) {
      sv[ib + r] = sr[r] * LOG2E;
      tv[ib + r] = tr[r] * LOG2E;
    }
  }
}

// ---------------------------------------------------------------------------
// K3: flash-GAT, R13's LDS-resident structure at DOUBLE occupancy.
// Block = 512 thr (8 waves x 16 rows = 128 i-rows); 64 KB LDS/block ->
// 2 resident blocks/CU = 16 waves/CU (R13: 8). __launch_bounds__(512,4)
// caps 128 VGPR/wave; per-wave row count halved (16 rows, acc 32 VGPR) so
// the kernel fits without spill and each wave's serial chain halves.
// 16-tile slice staged in 2 phases of 8 tiles (XOR-swizzled); adj prefetched
// one tile ahead; 5 barriers/block. Theory: flash is pure latency-bound at
// 8 waves/CU (R12 direct: all pipes <25%); 2x waves x half chain => ~2x.
// ---------------------------------------------------------------------------
__global__ __launch_bounds__(512, 4) void k_flash(const int* __restrict__ adj,
                                                  const short* __restrict__ HT2,
                                                  const float* __restrict__ sv,
                                                  const float* __restrict__ tv,
                                                  float* __restrict__ part,
                                                  float* __restrict__ lpart) {
  __shared__ short lds_s[32768];  // 64 KB: 8 tiles x 8 KB, swizzled
  unsigned* ldsw = (unsigned*)lds_s;
  const int tid = threadIdx.x;
  const int w = tid >> 6;   // 0..7
  const int L = tid & 63;
  const int lm = L & 15;
  const int q = L >> 4;
  const int sp = blockIdx.x & 15;  // j-split
  const int it = blockIdx.x >> 4;  // i-tile (64 x 128 rows)
  const int i0 = it * 128;

  const int row0 = i0 + 16 * w + lm;  // each wave: 16 rows
  const float s0 = sv[row0];
  const size_t ar0 = (size_t)row0 * NR;

  f32x4 acc[8];
#pragma unroll
  for (int nn = 0; nn < 8; ++nn) acc[nn] = (f32x4){0.f, 0.f, 0.f, 0.f};
  float l0 = 0.f;

  const int tile0 = sp * 16;  // 16 tiles per split
  // prologue: stage tile0's adj (the only HBM stream in the loop)
  int jb = tile0 * 32 + q * 8;
  int4 sa00 = *(const int4*)&adj[ar0 + jb];
  int4 sa01 = *(const int4*)&adj[ar0 + jb + 4];

  for (int t = 0; t < 16; ++t) {
    if ((t & 7) == 0) {  // stage phase t>>3: 8 tiles -> 64 KB LDS (swizzled)
      __syncthreads();   // prior phase's readers done
      const int pbase_t = tile0 + t;
#pragma unroll
      for (int z = 0; z < 8; ++z) {
        int id = z * 512 + tid;  // 0..4095 uint4s
        int tt = id >> 9;        // tile in phase
        int k = id & 511;
        int f = k >> 2, c = k & 3;
        uint4 v = *(const uint4*)&HT2[(size_t)(pbase_t + tt) * 4096 + k * 8];
        int cs = c ^ ((f >> 1) & 3);
        *(uint4*)&ldsw[tt * 2048 + f * 16 + cs * 4] = v;
      }
      __syncthreads();
    }
    // consume staged adj; prefetch next tile's adj
    int4 a00 = sa00, a01 = sa01;
    if (t + 1 < 16) {
      int jn = (tile0 + t + 1) * 32 + q * 8;
      sa00 = *(const int4*)&adj[ar0 + jn];
      sa01 = *(const int4*)&adj[ar0 + jn + 4];
    }
    const int jc = (tile0 + t) * 32 + q * 8;
    float4 tv0 = *(const float4*)&tv[jc];
    float4 tv1 = *(const float4*)&tv[jc + 4];
    const int tt = t & 7;
    short8 bf[8];
#pragma unroll
    for (int nn = 0; nn < 8; ++nn) {
      int f = nn * 16 + lm;
      bf[nn] = *(const short8*)&ldsw[tt * 2048 + f * 16 + ((q ^ ((f >> 1) & 3)) * 4)];
    }

    int av0[8] = {a00.x, a00.y, a00.z, a00.w, a01.x, a01.y, a01.z, a01.w};
    float tvl[8] = {tv0.x, tv0.y, tv0.z, tv0.w, tv1.x, tv1.y, tv1.z, tv1.w};
    short8 p0;
#pragma unroll
    for (int e = 0; e < 8; ++e) {
      // logits pre-scaled by log2e; lrelu(v) = max(v, 0.2v)
      float v0 = s0 + tvl[e];
      float e0 = fmaxf(v0, 0.2f * v0);
      float pp0 = (av0[e] > 0) ? __builtin_amdgcn_exp2f(e0) : 0.f;
      l0 += pp0;
      p0[e] = f2bf(pp0);
    }
#pragma unroll
    for (int nn = 0; nn < 8; ++nn)
      acc[nn] = __builtin_amdgcn_mfma_f32_16x16x32_bf16(p0, bf[nn], acc[nn], 0, 0, 0);
  }
  __syncthreads();  // slice LDS free -> reuse for epilogue

  // epilogue: wave-private LDS transpose (8 KB/wave = 64 KB), contiguous
  // float4 stores. Single-wave region: lgkmcnt orders, no barrier.
  float* my = (float*)lds_s + w * 2048;
#pragma unroll
  for (int nn = 0; nn < 8; ++nn)
#pragma unroll
    for (int r = 0; r < 4; ++r)
      my[(4 * q + r) * 128 + nn * 16 + lm] = acc[nn][r];
  float* pbase = part + ((size_t)sp * NR + i0 + 16 * w) * 128;
#pragma unroll
  for (int c = 0; c < 8; ++c) {
    int idx = (c * 64 + L) * 4;
    *(float4*)&pbase[idx] = *(const float4*)&my[idx];
  }

  // denominator: reduce the 4 q-replicas of each row
  l0 += __shfl_xor(l0, 16);
  l0 += __shfl_xor(l0, 32);
  if (q == 0) lpart[sp * NR + row0] = l0;
}

// ---------------------------------------------------------------------------
// K4: out[i][f] = sum_sp part / sum_sp lpart   (float4 vectorized)
// ---------------------------------------------------------------------------
__global__ __launch_bounds__(256) void k_reduce(const float* __restrict__ part,
                                                const float* __restrict__ lpart,
                                                float* __restrict__ out, int S) {
  int idx4 = blockIdx.x * 256 + threadIdx.x;
  int idx = idx4 * 4;  // i*128+f
  int i = idx >> 7;
  float4 sum = {0.f, 0.f, 0.f, 0.f};
  for (int sp = 0; sp < S; ++sp) {
    float4 v = *(const float4*)&part[(size_t)sp * (NR * 128) + idx];
    sum.x += v.x; sum.y += v.y; sum.z += v.z; sum.w += v.w;
  }
  float l = 0.f;
  for (int sp = 0; sp < S; ++sp) l += lpart[sp * NR + i];
  float inv = (l > 0.f) ? 1.f / l : 0.f;
  float4 o = {sum.x * inv, sum.y * inv, sum.z * inv, sum.w * inv};
  *(float4*)&out[idx] = o;
}

extern "C" void kernel_launch(void* const* d_in, const int* in_sizes, int n_in,
                              void* d_out, int out_size, void* d_ws, size_t ws_size,
                              hipStream_t stream) {
  const float* x = (const float*)d_in[0];    // 8192 x 256 fp32
  const int* adj = (const int*)d_in[1];      // 8192 x 8192 int32
  const float* W = (const float*)d_in[2];    // 256 x 128 fp32
  const float* a = (const float*)d_in[3];    // 256 x 1 fp32
  float* out = (float*)d_out;                // 8192 x 128 fp32

  char* ws = (char*)d_ws;
  short* HT2 = (short*)(ws + 0);          // 2 MB  bf16 h tiled [256][128][32]
  float* sv = (float*)(ws + 2097152);     // 32 KB
  float* tv = (float*)(ws + 2129920);     // 32 KB
  float* lpart = (float*)(ws + 2162688);  // 16*32 KB = 512 KB
  float* part = (float*)(ws + 2719744);   // 16 * 4 MB = 64 MB

  const int S = 16;  // j-splits: 64 i-tiles x 16 = 1024 blocks of 8 waves

  hipLaunchKernelGGL(k_gemm_h, dim3(128), dim3(256), 0, stream, x, W, a, HT2, sv, tv);
  hipLaunchKernelGGL(k_flash, dim3(64 * S), dim3(512), 0, stream, adj, HT2, sv, tv,
                     part, lpart);
  hipLaunchKernelGGL(k_reduce, dim3((NR * 128) / 1024), dim3(256), 0, stream, part,
                     lpart, out, S);
}